// Round 1
// baseline (1562.395 us; speedup 1.0000x reference)
//
#include <hip/hip_runtime.h>
#include <hip/hip_cooperative_groups.h>

namespace cg = cooperative_groups;

// MixHopConv, 8 GCN props on [N,2] fp32.
// R13: (a) de-quarter the edge sort — key is local_dst only, each thread owns
// 20 CONTIGUOUS sorted slots -> runs avg 16 (was 4) -> LDS atomics /3.6.
// (b) fuse all 8 layers into ONE cooperative kernel: ebuf[20] register-resident
// across layers (col2 read once, not 8x), d/inv/own-xs carried in registers,
// grid.sync() between props. Fallback to split kernels if cooperative launch
// is refused. col entry: (local_dst<<19)|src; local_dst 0..511; 512=sentinel.

constexpr int NN = 500000;
constexpr int NE = 8000000;
constexpr int STEP_DIM = 8;
constexpr int HIDM1 = 7;

constexpr int BSH  = 9;
constexpr int BNOD = 1 << BSH;                  // 512 nodes / bucket
constexpr int NBUK = (NN + BNOD - 1) / BNOD;    // 977
constexpr int SLOT = 10240;                     // 20 slots/thread * 512 (mean 8190, +22 sigma)
constexpr int WSLOT = 1280;                     // per-wave window (64 lanes * 20)
constexpr unsigned SENT = (unsigned)BNOD << 19; // sentinel -> dump row

constexpr int PA_NBLK = 500;
constexpr int PA_EPB  = NE / PA_NBLK;           // 16000 edges / chunk
constexpr int PA_QPB  = PA_EPB / 4;
constexpr int PA_SC   = NBUK + 1;               // starts2 stride (978)

typedef unsigned u32x4 __attribute__((ext_vector_type(4)));

// logical slot p -> physical (so thread l's 20 logical slots are read as
// 5 coalesced dwordx4: phys = w*1280 + (j>>2)*256 + l*4 + (j&3), j = p%20)
__device__ __forceinline__ int swiz(int p) {
  int w = p / WSLOT;
  int r = p - w * WSLOT;
  int tid = r / 20;
  int j = r - tid * 20;
  return w * WSLOT + ((j >> 2) << 8) + (tid << 2) + (j & 3);
}

__device__ __forceinline__ int wave_iscan(int v, int lane) {
#pragma unroll
  for (int off = 1; off < 64; off <<= 1) {
    int n = __shfl_up(v, off, 64);
    if (lane >= off) v += n;
  }
  return v;
}

// ---- phase 1: per-chunk LDS counting sort by bucket, linear stream-out -----

__global__ __launch_bounds__(512) void k_lsort(const int* __restrict__ src,
                                               const int* __restrict__ dst,
                                               unsigned* __restrict__ colraw,
                                               int* __restrict__ starts2) {
  __shared__ unsigned stage[PA_EPB];   // 62.5 KB
  __shared__ int hist[NBUK];
  __shared__ int tsum[512];
  int b = blockIdx.x, t = threadIdx.x;
  for (int h = t; h < NBUK; h += 512) hist[h] = 0;
  __syncthreads();
  const int4* d4p = (const int4*)dst + (size_t)b * PA_QPB;
  const int4* s4p = (const int4*)src + (size_t)b * PA_QPB;
  for (int i = t; i < PA_QPB; i += 512) {
    int4 d = d4p[i];
    atomicAdd(&hist[d.x >> BSH], 1);
    atomicAdd(&hist[d.y >> BSH], 1);
    atomicAdd(&hist[d.z >> BSH], 1);
    atomicAdd(&hist[d.w >> BSH], 1);
  }
  __syncthreads();
  int h0 = 2 * t, h1 = 2 * t + 1;
  int a0 = (h0 < NBUK) ? hist[h0] : 0;
  int a1 = (h1 < NBUK) ? hist[h1] : 0;
  tsum[t] = a0 + a1;
  __syncthreads();
  for (int o = 1; o < 512; o <<= 1) {
    int v = (t >= o) ? tsum[t - o] : 0;
    __syncthreads();
    tsum[t] += v;
    __syncthreads();
  }
  int ex = tsum[t] - (a0 + a1);
  __syncthreads();
  if (h0 < NBUK) hist[h0] = ex;
  if (h1 < NBUK) hist[h1] = ex + a0;
  __syncthreads();
  int* st = starts2 + (size_t)b * PA_SC;
  for (int h = t; h < NBUK; h += 512) st[h] = hist[h];
  if (t == 0) st[NBUK] = PA_EPB;
  __syncthreads();
  for (int i = t; i < PA_QPB; i += 512) {
    int4 d = d4p[i];
    int4 s = s4p[i];
    int p0 = atomicAdd(&hist[d.x >> BSH], 1);
    stage[p0] = ((unsigned)(d.x & (BNOD - 1)) << 19) | (unsigned)s.x;
    int p1 = atomicAdd(&hist[d.y >> BSH], 1);
    stage[p1] = ((unsigned)(d.y & (BNOD - 1)) << 19) | (unsigned)s.y;
    int p2 = atomicAdd(&hist[d.z >> BSH], 1);
    stage[p2] = ((unsigned)(d.z & (BNOD - 1)) << 19) | (unsigned)s.z;
    int p3 = atomicAdd(&hist[d.w >> BSH], 1);
    stage[p3] = ((unsigned)(d.w & (BNOD - 1)) << 19) | (unsigned)s.w;
  }
  __syncthreads();
  u32x4* out4 = (u32x4*)(colraw + (size_t)b * PA_EPB);
  for (int i = t; i < PA_QPB; i += 512) {
    u32x4 q;
    q[0] = stage[4 * i + 0];
    q[1] = stage[4 * i + 1];
    q[2] = stage[4 * i + 2];
    q[3] = stage[4 * i + 3];
    __builtin_nontemporal_store(q, out4 + i);
  }
}

// ---- phase 2: cooperative run copy + dst sort + swizzle --------------------
// Also emits dis[i] and the folded layer-0 gather table qtab.

__global__ __launch_bounds__(512) void k_sortA(const unsigned* __restrict__ colraw,
                                               const int* __restrict__ starts2,
                                               unsigned* __restrict__ col2,
                                               const float2* __restrict__ X,
                                               const float* __restrict__ W0,
                                               const float* __restrict__ step_emb,
                                               const int* __restrict__ step_index,
                                               float* __restrict__ dis,
                                               float2* __restrict__ qtab) {
  __shared__ unsigned stage[SLOT];     // 40 KB
  __shared__ int hist[BNOD];           // 2 KB (512 dst bins)
  __shared__ int rp[PA_NBLK + 1];      // run start positions (2 KB)
  __shared__ int rs[PA_NBLK];          // run source offsets (2 KB)
  __shared__ int wpart[8];
  int h = blockIdx.x, t = threadIdx.x;
  int wv = t >> 6, lane = t & 63;
  // run table from starts2 (one run per chunk)
  int s = 0, len = 0;
  if (t < PA_NBLK) {
    s = starts2[(size_t)t * PA_SC + h];
    len = starts2[(size_t)t * PA_SC + h + 1] - s;
  }
  hist[t] = 0;
  // wave scan of run lengths
  int incl = wave_iscan(len, lane);
  if (lane == 63) wpart[wv] = incl;
  __syncthreads();
  int wpre = 0, tot = 0;
#pragma unroll
  for (int k = 0; k < 8; ++k) {
    int pv = wpart[k];
    if (k < wv) wpre += pv;
    tot += pv;
  }
  int pos = wpre + incl - len;  // exclusive prefix
  if (t < PA_NBLK) {
    rp[t] = pos;
    rs[t] = s;
  }
  if (t == 511) rp[PA_NBLK] = tot;
  __syncthreads();
  int ns = tot;
  if (ns > SLOT) ns = SLOT;  // statistically never
  // cooperative run copy: one 16-lane group per run (line-local reads)
  {
    int g = t >> 4, gl = t & 15;  // 32 groups
    for (int r = g; r < PA_NBLK; r += 32) {
      int P = rp[r];
      int L = rp[r + 1] - P;
      const unsigned* rw = colraw + (size_t)r * PA_EPB + rs[r];
      for (int j = gl; j < L; j += 16) {
        int p = P + j;
        if (p < SLOT) stage[p] = rw[j];
      }
    }
  }
  __syncthreads();
  // histogram over local_dst (512 bins)
  for (int i = t; i < ns; i += 512)
    atomicAdd(&hist[stage[i] >> 19], 1);
  __syncthreads();
  int deg = hist[t];               // in-degree of node h*512+t
  int incl2 = wave_iscan(deg, lane);
  if (lane == 63) wpart[wv] = incl2;
  __syncthreads();
  int wpre2 = 0;
#pragma unroll
  for (int k = 0; k < 8; ++k) {
    if (k < wv) wpre2 += wpart[k];
  }
  hist[t] = wpre2 + incl2 - deg;   // exclusive prefix
  __syncthreads();
  unsigned* base = col2 + (size_t)h * SLOT;
  for (int i = t; i < ns; i += 512) {
    unsigned p = stage[i];
    int posQ = atomicAdd(&hist[(int)(p >> 19)], 1);
    if (posQ < SLOT) base[swiz(posQ)] = p;
  }
  for (int j = ns + t; j < SLOT; j += 512) base[swiz(j)] = SENT;
  // node init: dis + folded layer-0 gather table
  int i = (h << BSH) + t;
  if (i < NN) {
    float d = rsqrtf((float)deg + 1.0f);
    dis[i] = d;
    float2 x = X[i];
    const float* sv = step_emb + step_index[0] * STEP_DIM;
    float c1_0 = 0.f, c1_1 = 0.f;
#pragma unroll
    for (int j = 0; j < STEP_DIM; ++j) {
      c1_0 += sv[j] * W0[20 + (2 + j) * 2 + 0];
      c1_1 += sv[j] * W0[20 + (2 + j) * 2 + 1];
    }
    qtab[i] = make_float2(d * (x.x * W0[20] + x.y * W0[22] + c1_0),
                          d * (x.x * W0[21] + x.y * W0[23] + c1_1));
  }
}

// ---- shared layer helpers --------------------------------------------------

__device__ __forceinline__ void load_ebuf(const unsigned* __restrict__ col2,
                                          int b, int w, int l, unsigned* ebuf) {
  const unsigned* bp = col2 + (size_t)b * SLOT + w * WSLOT + l * 4;
#pragma unroll
  for (int g = 0; g < 5; ++g) {
    u32x4 v = __builtin_nontemporal_load((const u32x4*)(bp + g * 256));
    ebuf[g * 4 + 0] = v[0];
    ebuf[g * 4 + 1] = v[1];
    ebuf[g * 4 + 2] = v[2];
    ebuf[g * 4 + 3] = v[3];
  }
}

// 20 contiguous sorted slots per thread; runs avg 16 -> ~2.3 flushes/thread.
__device__ __forceinline__ void gather_acc(const unsigned* ebuf,
                                           const float2* tab, float* acc) {
  int cur = BNOD;
  float rx = 0.f, ry = 0.f;
#pragma unroll
  for (int g = 0; g < 5; ++g) {
    float2 vals[4];
#pragma unroll
    for (int r = 0; r < 4; ++r) vals[r] = tab[ebuf[g * 4 + r] & 0x7FFFF];
#pragma unroll
    for (int r = 0; r < 4; ++r) {
      int ld = (int)(ebuf[g * 4 + r] >> 19);
      if (ld != cur) {
        atomicAdd(&acc[cur * 2 + 0], rx);
        atomicAdd(&acc[cur * 2 + 1], ry);
        cur = ld;
        rx = vals[r].x;
        ry = vals[r].y;
      } else {
        rx += vals[r].x;
        ry += vals[r].y;
      }
    }
  }
  atomicAdd(&acc[cur * 2 + 0], rx);
  atomicAdd(&acc[cur * 2 + 1], ry);
}

// ---- fused 8-layer cooperative kernel --------------------------------------
// ebuf register-resident across all layers; d/inv/own-xs carried in registers.

__global__ __launch_bounds__(512, 8) void k_layers(
    const unsigned* __restrict__ col2,
    float2* qtab,                      // aliases bufA (reused as ping buffer)
    const float2* __restrict__ X,
    const float* __restrict__ dis,
    const float* __restrict__ W0,
    const float* __restrict__ b0,
    const float* __restrict__ step_emb,
    const int* __restrict__ step_index,
    const float* __restrict__ Wh,
    const float* __restrict__ bh,
    float2* bufB,
    float2* out) {
  cg::grid_group grid = cg::this_grid();
  __shared__ float acc[(BNOD + 1) * 2];
  int b = blockIdx.x, t = threadIdx.x;
  int w = t >> 6, l = t & 63;
  unsigned ebuf[20];
  load_ebuf(col2, b, w, l, ebuf);
  int i = (b << BSH) + t;
  bool act = i < NN;
  float d = dis[i];         // dis buffer padded to 500224; tail garbage unused
  float inv = 1.0f / d;
  // ---- layer 0 ----
  for (int j = t; j < (BNOD + 1) * 2; j += 512) acc[j] = 0.f;
  __syncthreads();
  gather_acc(ebuf, (const float2*)qtab, acc);
  __syncthreads();
  const float* sv = step_emb + step_index[0] * STEP_DIM;
  float c00 = b0[0] + b0[2], c01 = b0[1] + b0[3];
#pragma unroll
  for (int j = 0; j < STEP_DIM; ++j) {
    c00 += sv[j] * W0[(2 + j) * 2 + 0];
    c01 += sv[j] * W0[(2 + j) * 2 + 1];
  }
  float2 xsv = make_float2(0.f, 0.f);
  if (act) {
    float2 x = X[i];
    float2 qv = qtab[i];
    float h0 = c00 + x.x * W0[0] + x.y * W0[2] + d * (acc[t * 2 + 0] + qv.x);
    float h1 = c01 + x.x * W0[1] + x.y * W0[3] + d * (acc[t * 2 + 1] + qv.y);
    h0 = fmaxf(h0, 0.f);
    h1 = fmaxf(h1, 0.f);
    xsv = make_float2(d * h0, d * h1);
    bufB[i] = xsv;
  }
  grid.sync();
  // ---- hidden layers ----
  float2* curb = bufB;
  float2* nxtb = qtab;
#pragma unroll 1
  for (int L = 0; L < HIDM1; ++L) {
    for (int j = t; j < (BNOD + 1) * 2; j += 512) acc[j] = 0.f;
    __syncthreads();
    gather_acc(ebuf, (const float2*)curb, acc);
    __syncthreads();
    const float* W = Wh + L * 8;
    const float* bb = bh + L * 4;
    if (act) {
      float px = d * (acc[t * 2 + 0] + xsv.x);
      float py = d * (acc[t * 2 + 1] + xsv.y);
      float xx = xsv.x * inv, xy = xsv.y * inv;
      float h0 = bb[0] + bb[2] + xx * W[0] + xy * W[2] + px * W[4] + py * W[6];
      float h1 = bb[1] + bb[3] + xx * W[1] + xy * W[3] + px * W[5] + py * W[7];
      h0 = fmaxf(h0, 0.f);
      h1 = fmaxf(h1, 0.f);
      if (L == HIDM1 - 1) {
        out[i] = make_float2(h0, h1);
      } else {
        xsv = make_float2(d * h0, d * h1);
        nxtb[i] = xsv;
      }
    }
    if (L != HIDM1 - 1) grid.sync();
    float2* tmp = curb;
    curb = nxtb;
    nxtb = tmp;
  }
}

// ---- fallback split layer kernels (same new layout) ------------------------

__global__ __launch_bounds__(512, 8) void k_blayer0(const unsigned* __restrict__ col2,
                                                    const float2* __restrict__ qtab,
                                                    const float2* __restrict__ X,
                                                    const float* __restrict__ dis,
                                                    const float* __restrict__ W0,
                                                    const float* __restrict__ b0,
                                                    const float* __restrict__ step_emb,
                                                    const int* __restrict__ step_index,
                                                    float2* __restrict__ xs_out) {
  __shared__ float acc[(BNOD + 1) * 2];
  int b = blockIdx.x, t = threadIdx.x;
  for (int j = t; j < (BNOD + 1) * 2; j += 512) acc[j] = 0.f;
  __syncthreads();
  int w = t >> 6, l = t & 63;
  unsigned ebuf[20];
  load_ebuf(col2, b, w, l, ebuf);
  gather_acc(ebuf, qtab, acc);
  __syncthreads();
  const float* sv = step_emb + step_index[0] * STEP_DIM;
  float c00 = b0[0] + b0[2], c01 = b0[1] + b0[3];
#pragma unroll
  for (int j = 0; j < STEP_DIM; ++j) {
    c00 += sv[j] * W0[(2 + j) * 2 + 0];
    c01 += sv[j] * W0[(2 + j) * 2 + 1];
  }
  int i = (b << BSH) + t;
  if (i < NN) {
    float d = dis[i];
    float2 x = X[i];
    float2 qv = qtab[i];
    float h0 = c00 + x.x * W0[0] + x.y * W0[2] + d * (acc[t * 2 + 0] + qv.x);
    float h1 = c01 + x.x * W0[1] + x.y * W0[3] + d * (acc[t * 2 + 1] + qv.y);
    h0 = fmaxf(h0, 0.f);
    h1 = fmaxf(h1, 0.f);
    xs_out[i] = make_float2(d * h0, d * h1);
  }
}

__global__ __launch_bounds__(512, 8) void k_blayer(const unsigned* __restrict__ col2,
                                                   const float* __restrict__ dis,
                                                   const float2* __restrict__ xs_in,
                                                   const float* __restrict__ W,
                                                   const float* __restrict__ bb,
                                                   float2* __restrict__ xs_out,
                                                   float2* __restrict__ out,
                                                   int last) {
  __shared__ float acc[(BNOD + 1) * 2];
  int b = blockIdx.x, t = threadIdx.x;
  for (int j = t; j < (BNOD + 1) * 2; j += 512) acc[j] = 0.f;
  __syncthreads();
  int w = t >> 6, l = t & 63;
  unsigned ebuf[20];
  load_ebuf(col2, b, w, l, ebuf);
  gather_acc(ebuf, xs_in, acc);
  __syncthreads();
  int i = (b << BSH) + t;
  if (i < NN) {
    float d = dis[i];
    float2 xsv = xs_in[i];
    float inv = 1.0f / d;
    float xx = xsv.x * inv, xy = xsv.y * inv;
    float px = d * (acc[t * 2 + 0] + xsv.x);
    float py = d * (acc[t * 2 + 1] + xsv.y);
    float h0 = bb[0] + bb[2] + xx * W[0] + xy * W[2] + px * W[4] + py * W[6];
    float h1 = bb[1] + bb[3] + xx * W[1] + xy * W[3] + px * W[5] + py * W[7];
    h0 = fmaxf(h0, 0.f);
    h1 = fmaxf(h1, 0.f);
    if (last) {
      out[i] = make_float2(h0, h1);
    } else {
      xs_out[i] = make_float2(d * h0, d * h1);
    }
  }
}

// ---- driver ----------------------------------------------------------------

extern "C" void kernel_launch(void* const* d_in, const int* in_sizes, int n_in,
                              void* d_out, int out_size, void* d_ws, size_t ws_size,
                              hipStream_t stream) {
  const float2* X        = (const float2*)d_in[0];
  const int*    edge     = (const int*)d_in[1];
  const int*    src      = edge;
  const int*    dstp     = edge + NE;
  const int*    step_idx = (const int*)d_in[2];
  const float*  step_emb = (const float*)d_in[3];
  const float*  W0       = (const float*)d_in[4];
  const float*  b0       = (const float*)d_in[5];
  const float*  Wh       = (const float*)d_in[6];
  const float*  bbias    = (const float*)d_in[7];

  // ws ints: [col2: 977*10240][colraw: NE][starts2: 500*978 pad]
  //          [dis: 500224][bufA: 1000448][bufB: 1000448]
  int*      ip      = (int*)d_ws;
  unsigned* col2    = (unsigned*)ip;
  size_t    o       = (size_t)NBUK * SLOT;
  unsigned* colraw  = (unsigned*)(ip + o);  o += NE;
  int*      starts2 = ip + o;               o += ((size_t)PA_NBLK * PA_SC + 8) & ~(size_t)3;
  float*    dis     = (float*)(ip + o);     o += 500224;
  float2*   bufA    = (float2*)(ip + o);    o += 2 * 500224;
  float2*   bufB    = (float2*)(ip + o);

  k_lsort<<<PA_NBLK, 512, 0, stream>>>(src, dstp, colraw, starts2);
  k_sortA<<<NBUK, 512, 0, stream>>>(colraw, starts2, col2, X, W0,
                                    step_emb, step_idx, dis, bufA);

  const unsigned* a_col2 = col2;
  float2*         a_qtab = bufA;
  const float2*   a_X    = X;
  const float*    a_dis  = dis;
  const float*    a_W0   = W0;
  const float*    a_b0   = b0;
  const float*    a_se   = step_emb;
  const int*      a_si   = step_idx;
  const float*    a_Wh   = Wh;
  const float*    a_bh   = bbias;
  float2*         a_bufB = bufB;
  float2*         a_out  = (float2*)d_out;
  void* cargs[] = {&a_col2, &a_qtab, &a_X, &a_dis, &a_W0, &a_b0,
                   &a_se,   &a_si,   &a_Wh, &a_bh, &a_bufB, &a_out};
  hipError_t ce = hipLaunchCooperativeKernel(k_layers, dim3(NBUK), dim3(512),
                                             cargs, 0, stream);
  if (ce != hipSuccess) {
    (void)hipGetLastError();  // clear; fall back to split launches
    k_blayer0<<<NBUK, 512, 0, stream>>>(col2, bufA, X, dis, W0, b0,
                                        step_emb, step_idx, bufB);
    float2* cur = bufB;
    float2* nxt = bufA;
    for (int l = 0; l < HIDM1; ++l) {
      k_blayer<<<NBUK, 512, 0, stream>>>(col2, dis, cur, Wh + l * 8,
                                         bbias + l * 4, nxt, (float2*)d_out,
                                         l == HIDM1 - 1 ? 1 : 0);
      float2* tmp = cur;
      cur = nxt;
      nxt = tmp;
    }
  }
}

// Round 3
// 546.661 us; speedup vs baseline: 2.8581x; 2.8581x over previous
//
#include <hip/hip_runtime.h>

// MixHopConv, 8 GCN props on [N,2] fp32.
// R15 == R14 resubmitted (R14 bench died in broker infra, no kernel verdict).
// R14: cooperative fusion REVERTED (grid.sync() on ROCm = ~150us global atomic
// spin x7 -> 1.4ms; VALUBusy 0.94%). Back to split per-layer launches, keeping
// R13's de-quartered sort: key is local_dst only, each thread owns 20
// CONTIGUOUS sorted slots -> runs avg 16 (was 4) -> LDS atomic flushes /3.6,
// and k_sortA's histogram/scan shrinks 2048->512 bins.
// col entry: (local_dst<<19)|src; local_dst 0..511; 512=sentinel.

constexpr int NN = 500000;
constexpr int NE = 8000000;
constexpr int STEP_DIM = 8;
constexpr int HIDM1 = 7;

constexpr int BSH  = 9;
constexpr int BNOD = 1 << BSH;                  // 512 nodes / bucket
constexpr int NBUK = (NN + BNOD - 1) / BNOD;    // 977
constexpr int SLOT = 10240;                     // 20 slots/thread * 512 (mean 8190, +22 sigma)
constexpr int WSLOT = 1280;                     // per-wave window (64 lanes * 20)
constexpr unsigned SENT = (unsigned)BNOD << 19; // sentinel -> dump row

constexpr int PA_NBLK = 500;
constexpr int PA_EPB  = NE / PA_NBLK;           // 16000 edges / chunk
constexpr int PA_QPB  = PA_EPB / 4;
constexpr int PA_SC   = NBUK + 1;               // starts2 stride (978)

typedef unsigned u32x4 __attribute__((ext_vector_type(4)));

// logical slot p -> physical (so thread l's 20 logical slots are read as
// 5 coalesced dwordx4: phys = w*1280 + (j>>2)*256 + l*4 + (j&3), j = p%20)
__device__ __forceinline__ int swiz(int p) {
  int w = p / WSLOT;
  int r = p - w * WSLOT;
  int tid = r / 20;
  int j = r - tid * 20;
  return w * WSLOT + ((j >> 2) << 8) + (tid << 2) + (j & 3);
}

__device__ __forceinline__ int wave_iscan(int v, int lane) {
#pragma unroll
  for (int off = 1; off < 64; off <<= 1) {
    int n = __shfl_up(v, off, 64);
    if (lane >= off) v += n;
  }
  return v;
}

// ---- phase 1: per-chunk LDS counting sort by bucket, linear stream-out -----

__global__ __launch_bounds__(512) void k_lsort(const int* __restrict__ src,
                                               const int* __restrict__ dst,
                                               unsigned* __restrict__ colraw,
                                               int* __restrict__ starts2) {
  __shared__ unsigned stage[PA_EPB];   // 62.5 KB
  __shared__ int hist[NBUK];
  __shared__ int tsum[512];
  int b = blockIdx.x, t = threadIdx.x;
  for (int h = t; h < NBUK; h += 512) hist[h] = 0;
  __syncthreads();
  const int4* d4p = (const int4*)dst + (size_t)b * PA_QPB;
  const int4* s4p = (const int4*)src + (size_t)b * PA_QPB;
  for (int i = t; i < PA_QPB; i += 512) {
    int4 d = d4p[i];
    atomicAdd(&hist[d.x >> BSH], 1);
    atomicAdd(&hist[d.y >> BSH], 1);
    atomicAdd(&hist[d.z >> BSH], 1);
    atomicAdd(&hist[d.w >> BSH], 1);
  }
  __syncthreads();
  int h0 = 2 * t, h1 = 2 * t + 1;
  int a0 = (h0 < NBUK) ? hist[h0] : 0;
  int a1 = (h1 < NBUK) ? hist[h1] : 0;
  tsum[t] = a0 + a1;
  __syncthreads();
  for (int o = 1; o < 512; o <<= 1) {
    int v = (t >= o) ? tsum[t - o] : 0;
    __syncthreads();
    tsum[t] += v;
    __syncthreads();
  }
  int ex = tsum[t] - (a0 + a1);
  __syncthreads();
  if (h0 < NBUK) hist[h0] = ex;
  if (h1 < NBUK) hist[h1] = ex + a0;
  __syncthreads();
  int* st = starts2 + (size_t)b * PA_SC;
  for (int h = t; h < NBUK; h += 512) st[h] = hist[h];
  if (t == 0) st[NBUK] = PA_EPB;
  __syncthreads();
  for (int i = t; i < PA_QPB; i += 512) {
    int4 d = d4p[i];
    int4 s = s4p[i];
    int p0 = atomicAdd(&hist[d.x >> BSH], 1);
    stage[p0] = ((unsigned)(d.x & (BNOD - 1)) << 19) | (unsigned)s.x;
    int p1 = atomicAdd(&hist[d.y >> BSH], 1);
    stage[p1] = ((unsigned)(d.y & (BNOD - 1)) << 19) | (unsigned)s.y;
    int p2 = atomicAdd(&hist[d.z >> BSH], 1);
    stage[p2] = ((unsigned)(d.z & (BNOD - 1)) << 19) | (unsigned)s.z;
    int p3 = atomicAdd(&hist[d.w >> BSH], 1);
    stage[p3] = ((unsigned)(d.w & (BNOD - 1)) << 19) | (unsigned)s.w;
  }
  __syncthreads();
  u32x4* out4 = (u32x4*)(colraw + (size_t)b * PA_EPB);
  for (int i = t; i < PA_QPB; i += 512) {
    u32x4 q;
    q[0] = stage[4 * i + 0];
    q[1] = stage[4 * i + 1];
    q[2] = stage[4 * i + 2];
    q[3] = stage[4 * i + 3];
    __builtin_nontemporal_store(q, out4 + i);
  }
}

// ---- phase 2: cooperative run copy + dst sort + swizzle --------------------
// Also emits dis[i] and the folded layer-0 gather table qtab.

__global__ __launch_bounds__(512) void k_sortA(const unsigned* __restrict__ colraw,
                                               const int* __restrict__ starts2,
                                               unsigned* __restrict__ col2,
                                               const float2* __restrict__ X,
                                               const float* __restrict__ W0,
                                               const float* __restrict__ step_emb,
                                               const int* __restrict__ step_index,
                                               float* __restrict__ dis,
                                               float2* __restrict__ qtab) {
  __shared__ unsigned stage[SLOT];     // 40 KB
  __shared__ int hist[BNOD];           // 2 KB (512 dst bins)
  __shared__ int rp[PA_NBLK + 1];      // run start positions (2 KB)
  __shared__ int rs[PA_NBLK];          // run source offsets (2 KB)
  __shared__ int wpart[8];
  int h = blockIdx.x, t = threadIdx.x;
  int wv = t >> 6, lane = t & 63;
  // run table from starts2 (one run per chunk)
  int s = 0, len = 0;
  if (t < PA_NBLK) {
    s = starts2[(size_t)t * PA_SC + h];
    len = starts2[(size_t)t * PA_SC + h + 1] - s;
  }
  hist[t] = 0;
  // wave scan of run lengths
  int incl = wave_iscan(len, lane);
  if (lane == 63) wpart[wv] = incl;
  __syncthreads();
  int wpre = 0, tot = 0;
#pragma unroll
  for (int k = 0; k < 8; ++k) {
    int pv = wpart[k];
    if (k < wv) wpre += pv;
    tot += pv;
  }
  int pos = wpre + incl - len;  // exclusive prefix
  if (t < PA_NBLK) {
    rp[t] = pos;
    rs[t] = s;
  }
  if (t == 511) rp[PA_NBLK] = tot;
  __syncthreads();
  int ns = tot;
  if (ns > SLOT) ns = SLOT;  // statistically never
  // cooperative run copy: one 16-lane group per run (line-local reads)
  {
    int g = t >> 4, gl = t & 15;  // 32 groups
    for (int r = g; r < PA_NBLK; r += 32) {
      int P = rp[r];
      int L = rp[r + 1] - P;
      const unsigned* rw = colraw + (size_t)r * PA_EPB + rs[r];
      for (int j = gl; j < L; j += 16) {
        int p = P + j;
        if (p < SLOT) stage[p] = rw[j];
      }
    }
  }
  __syncthreads();
  // histogram over local_dst (512 bins)
  for (int i = t; i < ns; i += 512)
    atomicAdd(&hist[stage[i] >> 19], 1);
  __syncthreads();
  int deg = hist[t];               // in-degree of node h*512+t
  int incl2 = wave_iscan(deg, lane);
  if (lane == 63) wpart[wv] = incl2;
  __syncthreads();
  int wpre2 = 0;
#pragma unroll
  for (int k = 0; k < 8; ++k) {
    if (k < wv) wpre2 += wpart[k];
  }
  hist[t] = wpre2 + incl2 - deg;   // exclusive prefix
  __syncthreads();
  unsigned* base = col2 + (size_t)h * SLOT;
  for (int i = t; i < ns; i += 512) {
    unsigned p = stage[i];
    int posQ = atomicAdd(&hist[(int)(p >> 19)], 1);
    if (posQ < SLOT) base[swiz(posQ)] = p;
  }
  for (int j = ns + t; j < SLOT; j += 512) base[swiz(j)] = SENT;
  // node init: dis + folded layer-0 gather table
  int i = (h << BSH) + t;
  if (i < NN) {
    float d = rsqrtf((float)deg + 1.0f);
    dis[i] = d;
    float2 x = X[i];
    const float* sv = step_emb + step_index[0] * STEP_DIM;
    float c1_0 = 0.f, c1_1 = 0.f;
#pragma unroll
    for (int j = 0; j < STEP_DIM; ++j) {
      c1_0 += sv[j] * W0[20 + (2 + j) * 2 + 0];
      c1_1 += sv[j] * W0[20 + (2 + j) * 2 + 1];
    }
    qtab[i] = make_float2(d * (x.x * W0[20] + x.y * W0[22] + c1_0),
                          d * (x.x * W0[21] + x.y * W0[23] + c1_1));
  }
}

// ---- shared layer helpers --------------------------------------------------

__device__ __forceinline__ void load_ebuf(const unsigned* __restrict__ col2,
                                          int b, int w, int l, unsigned* ebuf) {
  const unsigned* bp = col2 + (size_t)b * SLOT + w * WSLOT + l * 4;
#pragma unroll
  for (int g = 0; g < 5; ++g) {
    u32x4 v = __builtin_nontemporal_load((const u32x4*)(bp + g * 256));
    ebuf[g * 4 + 0] = v[0];
    ebuf[g * 4 + 1] = v[1];
    ebuf[g * 4 + 2] = v[2];
    ebuf[g * 4 + 3] = v[3];
  }
}

// 20 contiguous sorted slots per thread; runs avg 16 -> ~2.3 flushes/thread.
__device__ __forceinline__ void gather_acc(const unsigned* ebuf,
                                           const float2* tab, float* acc) {
  int cur = BNOD;
  float rx = 0.f, ry = 0.f;
#pragma unroll
  for (int g = 0; g < 5; ++g) {
    float2 vals[4];
#pragma unroll
    for (int r = 0; r < 4; ++r) vals[r] = tab[ebuf[g * 4 + r] & 0x7FFFF];
#pragma unroll
    for (int r = 0; r < 4; ++r) {
      int ld = (int)(ebuf[g * 4 + r] >> 19);
      if (ld != cur) {
        atomicAdd(&acc[cur * 2 + 0], rx);
        atomicAdd(&acc[cur * 2 + 1], ry);
        cur = ld;
        rx = vals[r].x;
        ry = vals[r].y;
      } else {
        rx += vals[r].x;
        ry += vals[r].y;
      }
    }
  }
  atomicAdd(&acc[cur * 2 + 0], rx);
  atomicAdd(&acc[cur * 2 + 1], ry);
}

// ---- layer kernels ---------------------------------------------------------

__global__ __launch_bounds__(512, 8) void k_blayer0(const unsigned* __restrict__ col2,
                                                    const float2* __restrict__ qtab,
                                                    const float2* __restrict__ X,
                                                    const float* __restrict__ dis,
                                                    const float* __restrict__ W0,
                                                    const float* __restrict__ b0,
                                                    const float* __restrict__ step_emb,
                                                    const int* __restrict__ step_index,
                                                    float2* __restrict__ xs_out) {
  __shared__ float acc[(BNOD + 1) * 2];
  int b = blockIdx.x, t = threadIdx.x;
  for (int j = t; j < (BNOD + 1) * 2; j += 512) acc[j] = 0.f;
  __syncthreads();
  int w = t >> 6, l = t & 63;
  unsigned ebuf[20];
  load_ebuf(col2, b, w, l, ebuf);
  gather_acc(ebuf, qtab, acc);
  __syncthreads();
  const float* sv = step_emb + step_index[0] * STEP_DIM;
  float c00 = b0[0] + b0[2], c01 = b0[1] + b0[3];
#pragma unroll
  for (int j = 0; j < STEP_DIM; ++j) {
    c00 += sv[j] * W0[(2 + j) * 2 + 0];
    c01 += sv[j] * W0[(2 + j) * 2 + 1];
  }
  int i = (b << BSH) + t;
  if (i < NN) {
    float d = dis[i];
    float2 x = X[i];
    float2 qv = qtab[i];
    float h0 = c00 + x.x * W0[0] + x.y * W0[2] + d * (acc[t * 2 + 0] + qv.x);
    float h1 = c01 + x.x * W0[1] + x.y * W0[3] + d * (acc[t * 2 + 1] + qv.y);
    h0 = fmaxf(h0, 0.f);
    h1 = fmaxf(h1, 0.f);
    xs_out[i] = make_float2(d * h0, d * h1);
  }
}

__global__ __launch_bounds__(512, 8) void k_blayer(const unsigned* __restrict__ col2,
                                                   const float* __restrict__ dis,
                                                   const float2* __restrict__ xs_in,
                                                   const float* __restrict__ W,
                                                   const float* __restrict__ bb,
                                                   float2* __restrict__ xs_out,
                                                   float2* __restrict__ out,
                                                   int last) {
  __shared__ float acc[(BNOD + 1) * 2];
  int b = blockIdx.x, t = threadIdx.x;
  for (int j = t; j < (BNOD + 1) * 2; j += 512) acc[j] = 0.f;
  __syncthreads();
  int w = t >> 6, l = t & 63;
  unsigned ebuf[20];
  load_ebuf(col2, b, w, l, ebuf);
  gather_acc(ebuf, xs_in, acc);
  __syncthreads();
  int i = (b << BSH) + t;
  if (i < NN) {
    float d = dis[i];
    float2 xsv = xs_in[i];
    float inv = 1.0f / d;
    float xx = xsv.x * inv, xy = xsv.y * inv;
    float px = d * (acc[t * 2 + 0] + xsv.x);
    float py = d * (acc[t * 2 + 1] + xsv.y);
    float h0 = bb[0] + bb[2] + xx * W[0] + xy * W[2] + px * W[4] + py * W[6];
    float h1 = bb[1] + bb[3] + xx * W[1] + xy * W[3] + px * W[5] + py * W[7];
    h0 = fmaxf(h0, 0.f);
    h1 = fmaxf(h1, 0.f);
    if (last) {
      out[i] = make_float2(h0, h1);
    } else {
      xs_out[i] = make_float2(d * h0, d * h1);
    }
  }
}

// ---- driver ----------------------------------------------------------------

extern "C" void kernel_launch(void* const* d_in, const int* in_sizes, int n_in,
                              void* d_out, int out_size, void* d_ws, size_t ws_size,
                              hipStream_t stream) {
  const float2* X        = (const float2*)d_in[0];
  const int*    edge     = (const int*)d_in[1];
  const int*    src      = edge;
  const int*    dstp     = edge + NE;
  const int*    step_idx = (const int*)d_in[2];
  const float*  step_emb = (const float*)d_in[3];
  const float*  W0       = (const float*)d_in[4];
  const float*  b0       = (const float*)d_in[5];
  const float*  Wh       = (const float*)d_in[6];
  const float*  bbias    = (const float*)d_in[7];

  // ws ints: [col2: 977*10240][colraw: NE][starts2: 500*978 pad]
  //          [dis: 500224][bufA: 1000448][bufB: 1000448]
  int*      ip      = (int*)d_ws;
  unsigned* col2    = (unsigned*)ip;
  size_t    o       = (size_t)NBUK * SLOT;
  unsigned* colraw  = (unsigned*)(ip + o);  o += NE;
  int*      starts2 = ip + o;               o += ((size_t)PA_NBLK * PA_SC + 8) & ~(size_t)3;
  float*    dis     = (float*)(ip + o);     o += 500224;
  float2*   bufA    = (float2*)(ip + o);    o += 2 * 500224;
  float2*   bufB    = (float2*)(ip + o);

  k_lsort<<<PA_NBLK, 512, 0, stream>>>(src, dstp, colraw, starts2);
  k_sortA<<<NBUK, 512, 0, stream>>>(colraw, starts2, col2, X, W0,
                                    step_emb, step_idx, dis, bufA);

  k_blayer0<<<NBUK, 512, 0, stream>>>(col2, bufA, X, dis, W0, b0,
                                      step_emb, step_idx, bufB);
  float2* cur = bufB;
  float2* nxt = bufA;
  for (int l = 0; l < HIDM1; ++l) {
    k_blayer<<<NBUK, 512, 0, stream>>>(col2, dis, cur, Wh + l * 8,
                                       bbias + l * 4, nxt, (float2*)d_out,
                                       l == HIDM1 - 1 ? 1 : 0);
    float2* tmp = cur;
    cur = nxt;
    nxt = tmp;
  }
}

// Round 4
// 545.127 us; speedup vs baseline: 2.8661x; 1.0028x over previous
//
#include <hip/hip_runtime.h>

// MixHopConv, 8 GCN props on [N,2] fp32.
// R16: layer kernels are gather-LATENCY-bound, not LDS-bound (R15: /3.6 LDS
// atomics moved layers <2 us). Root cause: __launch_bounds__(512,8) caps VGPR
// at 64 -> compiler serializes the 20 gathers into 5 rounds of 4, each
// exposing ~300cy L2 latency. Fix: vals[20] loaded upfront (40 VGPR) +
// __launch_bounds__(512,4) (128-VGPR cap, 16 waves/CU). MLP 4->20 per thread.
// Also: col2 ebuf loads lose `nontemporal` so the 40 MB stream stays
// L3-resident across 8 layers (NT evicted it: R13 fetched ~39MB HBM/layer).
// col entry: (local_dst<<19)|src; local_dst 0..511; 512=sentinel.

constexpr int NN = 500000;
constexpr int NE = 8000000;
constexpr int STEP_DIM = 8;
constexpr int HIDM1 = 7;

constexpr int BSH  = 9;
constexpr int BNOD = 1 << BSH;                  // 512 nodes / bucket
constexpr int NBUK = (NN + BNOD - 1) / BNOD;    // 977
constexpr int SLOT = 10240;                     // 20 slots/thread * 512 (mean 8190, +22 sigma)
constexpr int WSLOT = 1280;                     // per-wave window (64 lanes * 20)
constexpr unsigned SENT = (unsigned)BNOD << 19; // sentinel -> dump row

constexpr int PA_NBLK = 500;
constexpr int PA_EPB  = NE / PA_NBLK;           // 16000 edges / chunk
constexpr int PA_QPB  = PA_EPB / 4;
constexpr int PA_SC   = NBUK + 1;               // starts2 stride (978)

typedef unsigned u32x4 __attribute__((ext_vector_type(4)));

// logical slot p -> physical (so thread l's 20 logical slots are read as
// 5 coalesced dwordx4: phys = w*1280 + (j>>2)*256 + l*4 + (j&3), j = p%20)
__device__ __forceinline__ int swiz(int p) {
  int w = p / WSLOT;
  int r = p - w * WSLOT;
  int tid = r / 20;
  int j = r - tid * 20;
  return w * WSLOT + ((j >> 2) << 8) + (tid << 2) + (j & 3);
}

__device__ __forceinline__ int wave_iscan(int v, int lane) {
#pragma unroll
  for (int off = 1; off < 64; off <<= 1) {
    int n = __shfl_up(v, off, 64);
    if (lane >= off) v += n;
  }
  return v;
}

// ---- phase 1: per-chunk LDS counting sort by bucket, linear stream-out -----

__global__ __launch_bounds__(512) void k_lsort(const int* __restrict__ src,
                                               const int* __restrict__ dst,
                                               unsigned* __restrict__ colraw,
                                               int* __restrict__ starts2) {
  __shared__ unsigned stage[PA_EPB];   // 62.5 KB
  __shared__ int hist[NBUK];
  __shared__ int tsum[512];
  int b = blockIdx.x, t = threadIdx.x;
  for (int h = t; h < NBUK; h += 512) hist[h] = 0;
  __syncthreads();
  const int4* d4p = (const int4*)dst + (size_t)b * PA_QPB;
  const int4* s4p = (const int4*)src + (size_t)b * PA_QPB;
  for (int i = t; i < PA_QPB; i += 512) {
    int4 d = d4p[i];
    atomicAdd(&hist[d.x >> BSH], 1);
    atomicAdd(&hist[d.y >> BSH], 1);
    atomicAdd(&hist[d.z >> BSH], 1);
    atomicAdd(&hist[d.w >> BSH], 1);
  }
  __syncthreads();
  int h0 = 2 * t, h1 = 2 * t + 1;
  int a0 = (h0 < NBUK) ? hist[h0] : 0;
  int a1 = (h1 < NBUK) ? hist[h1] : 0;
  tsum[t] = a0 + a1;
  __syncthreads();
  for (int o = 1; o < 512; o <<= 1) {
    int v = (t >= o) ? tsum[t - o] : 0;
    __syncthreads();
    tsum[t] += v;
    __syncthreads();
  }
  int ex = tsum[t] - (a0 + a1);
  __syncthreads();
  if (h0 < NBUK) hist[h0] = ex;
  if (h1 < NBUK) hist[h1] = ex + a0;
  __syncthreads();
  int* st = starts2 + (size_t)b * PA_SC;
  for (int h = t; h < NBUK; h += 512) st[h] = hist[h];
  if (t == 0) st[NBUK] = PA_EPB;
  __syncthreads();
  for (int i = t; i < PA_QPB; i += 512) {
    int4 d = d4p[i];
    int4 s = s4p[i];
    int p0 = atomicAdd(&hist[d.x >> BSH], 1);
    stage[p0] = ((unsigned)(d.x & (BNOD - 1)) << 19) | (unsigned)s.x;
    int p1 = atomicAdd(&hist[d.y >> BSH], 1);
    stage[p1] = ((unsigned)(d.y & (BNOD - 1)) << 19) | (unsigned)s.y;
    int p2 = atomicAdd(&hist[d.z >> BSH], 1);
    stage[p2] = ((unsigned)(d.z & (BNOD - 1)) << 19) | (unsigned)s.z;
    int p3 = atomicAdd(&hist[d.w >> BSH], 1);
    stage[p3] = ((unsigned)(d.w & (BNOD - 1)) << 19) | (unsigned)s.w;
  }
  __syncthreads();
  u32x4* out4 = (u32x4*)(colraw + (size_t)b * PA_EPB);
  for (int i = t; i < PA_QPB; i += 512) {
    u32x4 q;
    q[0] = stage[4 * i + 0];
    q[1] = stage[4 * i + 1];
    q[2] = stage[4 * i + 2];
    q[3] = stage[4 * i + 3];
    __builtin_nontemporal_store(q, out4 + i);
  }
}

// ---- phase 2: cooperative run copy + dst sort + swizzle --------------------
// Also emits dis[i] and the folded layer-0 gather table qtab.

__global__ __launch_bounds__(512) void k_sortA(const unsigned* __restrict__ colraw,
                                               const int* __restrict__ starts2,
                                               unsigned* __restrict__ col2,
                                               const float2* __restrict__ X,
                                               const float* __restrict__ W0,
                                               const float* __restrict__ step_emb,
                                               const int* __restrict__ step_index,
                                               float* __restrict__ dis,
                                               float2* __restrict__ qtab) {
  __shared__ unsigned stage[SLOT];     // 40 KB
  __shared__ int hist[BNOD];           // 2 KB (512 dst bins)
  __shared__ int rp[PA_NBLK + 1];      // run start positions (2 KB)
  __shared__ int rs[PA_NBLK];          // run source offsets (2 KB)
  __shared__ int wpart[8];
  int h = blockIdx.x, t = threadIdx.x;
  int wv = t >> 6, lane = t & 63;
  // run table from starts2 (one run per chunk)
  int s = 0, len = 0;
  if (t < PA_NBLK) {
    s = starts2[(size_t)t * PA_SC + h];
    len = starts2[(size_t)t * PA_SC + h + 1] - s;
  }
  hist[t] = 0;
  // wave scan of run lengths
  int incl = wave_iscan(len, lane);
  if (lane == 63) wpart[wv] = incl;
  __syncthreads();
  int wpre = 0, tot = 0;
#pragma unroll
  for (int k = 0; k < 8; ++k) {
    int pv = wpart[k];
    if (k < wv) wpre += pv;
    tot += pv;
  }
  int pos = wpre + incl - len;  // exclusive prefix
  if (t < PA_NBLK) {
    rp[t] = pos;
    rs[t] = s;
  }
  if (t == 511) rp[PA_NBLK] = tot;
  __syncthreads();
  int ns = tot;
  if (ns > SLOT) ns = SLOT;  // statistically never
  // cooperative run copy: one 16-lane group per run (line-local reads)
  {
    int g = t >> 4, gl = t & 15;  // 32 groups
    for (int r = g; r < PA_NBLK; r += 32) {
      int P = rp[r];
      int L = rp[r + 1] - P;
      const unsigned* rw = colraw + (size_t)r * PA_EPB + rs[r];
      for (int j = gl; j < L; j += 16) {
        int p = P + j;
        if (p < SLOT) stage[p] = rw[j];
      }
    }
  }
  __syncthreads();
  // histogram over local_dst (512 bins)
  for (int i = t; i < ns; i += 512)
    atomicAdd(&hist[stage[i] >> 19], 1);
  __syncthreads();
  int deg = hist[t];               // in-degree of node h*512+t
  int incl2 = wave_iscan(deg, lane);
  if (lane == 63) wpart[wv] = incl2;
  __syncthreads();
  int wpre2 = 0;
#pragma unroll
  for (int k = 0; k < 8; ++k) {
    if (k < wv) wpre2 += wpart[k];
  }
  hist[t] = wpre2 + incl2 - deg;   // exclusive prefix
  __syncthreads();
  unsigned* base = col2 + (size_t)h * SLOT;
  for (int i = t; i < ns; i += 512) {
    unsigned p = stage[i];
    int posQ = atomicAdd(&hist[(int)(p >> 19)], 1);
    if (posQ < SLOT) base[swiz(posQ)] = p;
  }
  for (int j = ns + t; j < SLOT; j += 512) base[swiz(j)] = SENT;
  // node init: dis + folded layer-0 gather table
  int i = (h << BSH) + t;
  if (i < NN) {
    float d = rsqrtf((float)deg + 1.0f);
    dis[i] = d;
    float2 x = X[i];
    const float* sv = step_emb + step_index[0] * STEP_DIM;
    float c1_0 = 0.f, c1_1 = 0.f;
#pragma unroll
    for (int j = 0; j < STEP_DIM; ++j) {
      c1_0 += sv[j] * W0[20 + (2 + j) * 2 + 0];
      c1_1 += sv[j] * W0[20 + (2 + j) * 2 + 1];
    }
    qtab[i] = make_float2(d * (x.x * W0[20] + x.y * W0[22] + c1_0),
                          d * (x.x * W0[21] + x.y * W0[23] + c1_1));
  }
}

// ---- shared layer helpers --------------------------------------------------

// cached (non-NT) loads: col2 (40 MB) stays L3-resident across the 8 layers
__device__ __forceinline__ void load_ebuf(const unsigned* __restrict__ col2,
                                          int b, int w, int l, unsigned* ebuf) {
  const unsigned* bp = col2 + (size_t)b * SLOT + w * WSLOT + l * 4;
#pragma unroll
  for (int g = 0; g < 5; ++g) {
    u32x4 v = *(const u32x4*)(bp + g * 256);
    ebuf[g * 4 + 0] = v[0];
    ebuf[g * 4 + 1] = v[1];
    ebuf[g * 4 + 2] = v[2];
    ebuf[g * 4 + 3] = v[3];
  }
}

// All 20 gathers issued upfront (40 VGPRs of values in flight), THEN the
// run-scan. Requires the 128-VGPR cap (launch_bounds 512,4).
__device__ __forceinline__ void gather_acc(const unsigned* ebuf,
                                           const float2* __restrict__ tab,
                                           float* acc) {
  float2 vals[20];
#pragma unroll
  for (int j = 0; j < 20; ++j) vals[j] = tab[ebuf[j] & 0x7FFFF];
  int cur = BNOD;
  float rx = 0.f, ry = 0.f;
#pragma unroll
  for (int j = 0; j < 20; ++j) {
    int ld = (int)(ebuf[j] >> 19);
    if (ld != cur) {
      atomicAdd(&acc[cur * 2 + 0], rx);
      atomicAdd(&acc[cur * 2 + 1], ry);
      cur = ld;
      rx = vals[j].x;
      ry = vals[j].y;
    } else {
      rx += vals[j].x;
      ry += vals[j].y;
    }
  }
  atomicAdd(&acc[cur * 2 + 0], rx);
  atomicAdd(&acc[cur * 2 + 1], ry);
}

// ---- layer kernels ---------------------------------------------------------

__global__ __launch_bounds__(512, 4) void k_blayer0(const unsigned* __restrict__ col2,
                                                    const float2* __restrict__ qtab,
                                                    const float2* __restrict__ X,
                                                    const float* __restrict__ dis,
                                                    const float* __restrict__ W0,
                                                    const float* __restrict__ b0,
                                                    const float* __restrict__ step_emb,
                                                    const int* __restrict__ step_index,
                                                    float2* __restrict__ xs_out) {
  __shared__ float acc[(BNOD + 1) * 2];
  int b = blockIdx.x, t = threadIdx.x;
  for (int j = t; j < (BNOD + 1) * 2; j += 512) acc[j] = 0.f;
  __syncthreads();
  int w = t >> 6, l = t & 63;
  unsigned ebuf[20];
  load_ebuf(col2, b, w, l, ebuf);
  gather_acc(ebuf, qtab, acc);
  __syncthreads();
  const float* sv = step_emb + step_index[0] * STEP_DIM;
  float c00 = b0[0] + b0[2], c01 = b0[1] + b0[3];
#pragma unroll
  for (int j = 0; j < STEP_DIM; ++j) {
    c00 += sv[j] * W0[(2 + j) * 2 + 0];
    c01 += sv[j] * W0[(2 + j) * 2 + 1];
  }
  int i = (b << BSH) + t;
  if (i < NN) {
    float d = dis[i];
    float2 x = X[i];
    float2 qv = qtab[i];
    float h0 = c00 + x.x * W0[0] + x.y * W0[2] + d * (acc[t * 2 + 0] + qv.x);
    float h1 = c01 + x.x * W0[1] + x.y * W0[3] + d * (acc[t * 2 + 1] + qv.y);
    h0 = fmaxf(h0, 0.f);
    h1 = fmaxf(h1, 0.f);
    xs_out[i] = make_float2(d * h0, d * h1);
  }
}

__global__ __launch_bounds__(512, 4) void k_blayer(const unsigned* __restrict__ col2,
                                                   const float* __restrict__ dis,
                                                   const float2* __restrict__ xs_in,
                                                   const float* __restrict__ W,
                                                   const float* __restrict__ bb,
                                                   float2* __restrict__ xs_out,
                                                   float2* __restrict__ out,
                                                   int last) {
  __shared__ float acc[(BNOD + 1) * 2];
  int b = blockIdx.x, t = threadIdx.x;
  for (int j = t; j < (BNOD + 1) * 2; j += 512) acc[j] = 0.f;
  __syncthreads();
  int w = t >> 6, l = t & 63;
  unsigned ebuf[20];
  load_ebuf(col2, b, w, l, ebuf);
  gather_acc(ebuf, xs_in, acc);
  __syncthreads();
  int i = (b << BSH) + t;
  if (i < NN) {
    float d = dis[i];
    float2 xsv = xs_in[i];
    float inv = 1.0f / d;
    float xx = xsv.x * inv, xy = xsv.y * inv;
    float px = d * (acc[t * 2 + 0] + xsv.x);
    float py = d * (acc[t * 2 + 1] + xsv.y);
    float h0 = bb[0] + bb[2] + xx * W[0] + xy * W[2] + px * W[4] + py * W[6];
    float h1 = bb[1] + bb[3] + xx * W[1] + xy * W[3] + px * W[5] + py * W[7];
    h0 = fmaxf(h0, 0.f);
    h1 = fmaxf(h1, 0.f);
    if (last) {
      out[i] = make_float2(h0, h1);
    } else {
      xs_out[i] = make_float2(d * h0, d * h1);
    }
  }
}

// ---- driver ----------------------------------------------------------------

extern "C" void kernel_launch(void* const* d_in, const int* in_sizes, int n_in,
                              void* d_out, int out_size, void* d_ws, size_t ws_size,
                              hipStream_t stream) {
  const float2* X        = (const float2*)d_in[0];
  const int*    edge     = (const int*)d_in[1];
  const int*    src      = edge;
  const int*    dstp     = edge + NE;
  const int*    step_idx = (const int*)d_in[2];
  const float*  step_emb = (const float*)d_in[3];
  const float*  W0       = (const float*)d_in[4];
  const float*  b0       = (const float*)d_in[5];
  const float*  Wh       = (const float*)d_in[6];
  const float*  bbias    = (const float*)d_in[7];

  // ws ints: [col2: 977*10240][colraw: NE][starts2: 500*978 pad]
  //          [dis: 500224][bufA: 1000448][bufB: 1000448]
  int*      ip      = (int*)d_ws;
  unsigned* col2    = (unsigned*)ip;
  size_t    o       = (size_t)NBUK * SLOT;
  unsigned* colraw  = (unsigned*)(ip + o);  o += NE;
  int*      starts2 = ip + o;               o += ((size_t)PA_NBLK * PA_SC + 8) & ~(size_t)3;
  float*    dis     = (float*)(ip + o);     o += 500224;
  float2*   bufA    = (float2*)(ip + o);    o += 2 * 500224;
  float2*   bufB    = (float2*)(ip + o);

  k_lsort<<<PA_NBLK, 512, 0, stream>>>(src, dstp, colraw, starts2);
  k_sortA<<<NBUK, 512, 0, stream>>>(colraw, starts2, col2, X, W0,
                                    step_emb, step_idx, dis, bufA);

  k_blayer0<<<NBUK, 512, 0, stream>>>(col2, bufA, X, dis, W0, b0,
                                      step_emb, step_idx, bufB);
  float2* cur = bufB;
  float2* nxt = bufA;
  for (int l = 0; l < HIDM1; ++l) {
    k_blayer<<<NBUK, 512, 0, stream>>>(col2, dis, cur, Wh + l * 8,
                                       bbias + l * 4, nxt, (float2*)d_out,
                                       l == HIDM1 - 1 ? 1 : 0);
    float2* tmp = cur;
    cur = nxt;
    nxt = tmp;
  }
}